// Round 1
// baseline (533.647 us; speedup 1.0000x reference)
//
#include <hip/hip_runtime.h>
#include <hip/hip_bf16.h>
#include <cstdint>

#define E_DIM   1280
#define NHEADS  20
#define HDIM    64
#define QKV_LD  3840   // 3*E

typedef __attribute__((ext_vector_type(8))) short bf8_t;   // 8 bf16 (4 VGPRs)
typedef __attribute__((ext_vector_type(4))) float f4_t;    // MFMA accumulator

__device__ __forceinline__ short f2bs(float f) {
    union { __hip_bfloat16 h; short s; } u;
    u.h = __float2bfloat16(f);
    return u.s;
}

__device__ __forceinline__ f4_t mfma16(bf8_t a, bf8_t b, f4_t c) {
    return __builtin_amdgcn_mfma_f32_16x16x32_bf16(a, b, c, 0, 0, 0);
}

// async global->LDS, 16B per lane. LDS dest must be wave-uniform base; HW writes base + lane*16.
__device__ __forceinline__ void gl_lds16(const void* g, void* l) {
    auto gp = reinterpret_cast<__attribute__((address_space(1))) unsigned int*>(
        reinterpret_cast<uintptr_t>(g));
    auto lp = reinterpret_cast<__attribute__((address_space(3))) unsigned int*>(
        reinterpret_cast<uintptr_t>(l));
    __builtin_amdgcn_global_load_lds(gp, lp, 16, 0, 0);
}

// ---------------- prep: casts + weight concat + bias concat ----------------
__device__ __forceinline__ void cvt8(__hip_bfloat16* dst, const float* src, float sc) {
    float4 a = *(const float4*)src;
    float4 b = *(const float4*)(src + 4);
    bf8_t v;
    v[0] = f2bs(a.x * sc); v[1] = f2bs(a.y * sc); v[2] = f2bs(a.z * sc); v[3] = f2bs(a.w * sc);
    v[4] = f2bs(b.x * sc); v[5] = f2bs(b.y * sc); v[6] = f2bs(b.z * sc); v[7] = f2bs(b.w * sc);
    *(bf8_t*)dst = v;
}

__global__ __launch_bounds__(256) void prep_kernel(
    const float* __restrict__ x,
    const float* __restrict__ wq, const float* __restrict__ wk,
    const float* __restrict__ wv, const float* __restrict__ wo,
    const float* __restrict__ bq, const float* __restrict__ bk, const float* __restrict__ bv,
    __hip_bfloat16* __restrict__ xbf, __hip_bfloat16* __restrict__ wqkv,
    __hip_bfloat16* __restrict__ wobf, float* __restrict__ bqkv,
    long nx8, long nw8, long nb8)
{
    long u = (long)blockIdx.x * 256 + threadIdx.x;
    const float scale = 0.125f;  // d^-0.5, d = 64 (folded into Wq/bq)
    if (u < nx8) { cvt8(xbf + u * 8, x + u * 8, 1.0f); return; }
    u -= nx8;
    if (u < 3 * nw8) {
        long e = u * 8;
        long w1 = nw8 * 8;
        const float* src; float sc;
        if (e < w1)            { src = wq + e;           sc = scale; }
        else if (e < 2 * w1)   { src = wk + (e - w1);    sc = 1.0f; }
        else                   { src = wv + (e - 2*w1);  sc = 1.0f; }
        cvt8(wqkv + e, src, sc);
        return;
    }
    u -= 3 * nw8;
    if (u < nw8) { cvt8(wobf + u * 8, wo + u * 8, 1.0f); return; }
    u -= nw8;
    if (u < nb8) {
        long e = u * 8;
        #pragma unroll
        for (int j = 0; j < 8; j++) {
            long i = e + j;
            float v;
            if (i < E_DIM)           v = bq[i] * scale;
            else if (i < 2 * E_DIM)  v = bk[i - E_DIM];
            else                     v = bv[i - 2 * E_DIM];
            bqkv[i] = v;
        }
    }
}

// ---------------- m97-style NT GEMM: C = A(MxK) * B(NxK)^T + bias ----------------
// A, B bf16 row-major stride K. Exact tiles assumed: M%128==0, N%128==0, K%32==0.
template<bool BF16_OUT>
__global__ __launch_bounds__(256, 3) void gemm_nt(
    const __hip_bfloat16* __restrict__ A, const __hip_bfloat16* __restrict__ Bw,
    const float* __restrict__ bias, void* __restrict__ Cout,
    int M, int N, int K, int ldc)
{
    __shared__ __align__(16) __hip_bfloat16 As[128 * 32];
    __shared__ __align__(16) __hip_bfloat16 Bs[128 * 32];
    const int t = threadIdx.x;
    const int wv = t >> 6;
    const int ln = t & 63;
    const int m16 = ln & 15, q4 = ln >> 4;
    const int row0 = blockIdx.y * 128, col0 = blockIdx.x * 128;
    const int wm = (wv >> 1) * 64, wn = (wv & 1) * 64;

    f4_t acc[4][4] = {};

    for (int k0 = 0; k0 < K; k0 += 32) {
        #pragma unroll
        for (int i = 0; i < 2; i++) {
            int s = i * 256 + t;
            int r = s >> 2, c = s & 3;
            gl_lds16(A + (size_t)(row0 + r) * K + k0 + c * 8,
                     As + (size_t)(i * 256 + wv * 64) * 8);
        }
        #pragma unroll
        for (int i = 0; i < 2; i++) {
            int s = i * 256 + t;
            int r = s >> 2, c = s & 3;
            gl_lds16(Bw + (size_t)(col0 + r) * K + k0 + c * 8,
                     Bs + (size_t)(i * 256 + wv * 64) * 8);
        }
        __syncthreads();
        bf8_t af[4], bfr[4];
        #pragma unroll
        for (int mt = 0; mt < 4; mt++)
            af[mt] = *(const bf8_t*)&As[(wm + mt * 16 + m16) * 32 + q4 * 8];
        #pragma unroll
        for (int nt = 0; nt < 4; nt++)
            bfr[nt] = *(const bf8_t*)&Bs[(wn + nt * 16 + m16) * 32 + q4 * 8];
        #pragma unroll
        for (int mt = 0; mt < 4; mt++)
            #pragma unroll
            for (int nt = 0; nt < 4; nt++)
                acc[mt][nt] = mfma16(af[mt], bfr[nt], acc[mt][nt]);
        __syncthreads();
    }

    // epilogue: C/D layout col = lane&15, row = (lane>>4)*4 + reg
    #pragma unroll
    for (int nt = 0; nt < 4; nt++) {
        int cg = col0 + wn + nt * 16 + m16;
        float bv = bias[cg];
        #pragma unroll
        for (int mt = 0; mt < 4; mt++) {
            #pragma unroll
            for (int r = 0; r < 4; r++) {
                int rg = row0 + wm + mt * 16 + q4 * 4 + r;
                float v = acc[mt][nt][r] + bv;
                if constexpr (BF16_OUT)
                    ((__hip_bfloat16*)Cout)[(long)rg * ldc + cg] = __float2bfloat16(v);
                else
                    ((float*)Cout)[(long)rg * ldc + cg] = v;
            }
        }
    }
}

// ---------------- RoPE (in place on q,k sections of qkv) ----------------
__global__ __launch_bounds__(256) void rope_kernel(
    __hip_bfloat16* __restrict__ qkv, const int* __restrict__ cu, int B, int T)
{
    long idx = (long)blockIdx.x * 256 + threadIdx.x;  // (t, h, i) with i fastest
    int i = idx & 31;
    long r = idx >> 5;
    int h = (int)(r % NHEADS);
    int tok = (int)(r / NHEADS);
    if (tok >= T) return;
    int pos = tok;
    for (int b = 1; b <= B; b++) if (tok >= cu[b]) pos = tok - cu[b];
    // inv_freq = 10000^(-i/32) = 2^(-i*log2(10000)/32)
    float f = (float)pos * exp2f(-(float)i * 0.41524100558003436f);
    float s, c;
    sincosf(f, &s, &c);
    long base = (long)tok * QKV_LD + h * HDIM + i;
    // q
    {
        float q1 = __bfloat162float(qkv[base]);
        float q2 = __bfloat162float(qkv[base + 32]);
        qkv[base]      = __float2bfloat16(q1 * c - q2 * s);
        qkv[base + 32] = __float2bfloat16(q2 * c + q1 * s);
    }
    // k
    {
        long kb = base + E_DIM;
        float k1 = __bfloat162float(qkv[kb]);
        float k2 = __bfloat162float(qkv[kb + 32]);
        qkv[kb]      = __float2bfloat16(k1 * c - k2 * s);
        qkv[kb + 32] = __float2bfloat16(k2 * c + k1 * s);
    }
}

// ---------------- V transpose: (T, h, d) -> (h*d, T), L2-relying gather ----------------
__global__ __launch_bounds__(256) void vtrans_kernel(
    const __hip_bfloat16* __restrict__ qkv, __hip_bfloat16* __restrict__ vt, int T)
{
    long u = (long)blockIdx.x * 256 + threadIdx.x;  // one 16B output chunk (8 tokens, one (h,d))
    int tchunks = T >> 3;
    int tc = (int)(u % tchunks);
    int hd = (int)(u / tchunks);
    if (hd >= E_DIM) return;
    long t0 = (long)tc * 8;
    bf8_t v;
    #pragma unroll
    for (int j = 0; j < 8; j++)
        v[j] = *(const short*)&qkv[(t0 + j) * QKV_LD + 2 * E_DIM + hd];
    *(bf8_t*)&vt[(long)hd * T + t0] = v;
}

// ---------------- flash attention: 1 block = 64 q-rows of one (seq, head) ----------------
__global__ __launch_bounds__(256, 2) void attn_kernel(
    const __hip_bfloat16* __restrict__ qkv, const __hip_bfloat16* __restrict__ vt,
    const int* __restrict__ cu, __hip_bfloat16* __restrict__ obuf, int B, int T)
{
    __shared__ __align__(16) __hip_bfloat16 Qs[64 * 72];        // 64 rows x 64 dims, +8 pad
    __shared__ __align__(16) __hip_bfloat16 Ks[128 * 72];       // 128 keys x 64 dims, +8 pad
    __shared__ __align__(16) __hip_bfloat16 Vs[64 * 136];       // 64 dims x 128 keys, +8 pad
    __shared__ __align__(16) __hip_bfloat16 Ps[4 * 16 * 136];   // per-wave 16 x 128 P tile

    int idx = blockIdx.x;
    int h = idx % NHEADS;
    int gt = idx / NHEADS;
    int b = 0, l = 0, seq0 = 0;
    for (; b < B; ++b) {
        seq0 = cu[b];
        l = cu[b + 1] - seq0;
        int nt = (l + 63) >> 6;
        if (gt < nt) break;
        gt -= nt;
    }
    if (b == B) return;
    int q0 = gt * 64;

    const int t = threadIdx.x;
    const int wv = t >> 6, ln = t & 63;
    const int m16 = ln & 15, q4 = ln >> 4;

    // stage Q tile (zero-fill invalid rows)
    #pragma unroll
    for (int i = 0; i < 2; i++) {
        int s = i * 256 + t;
        int r = s >> 3, c = s & 7;
        bf8_t v = 0;
        if (q0 + r < l)
            v = *(const bf8_t*)(qkv + (long)(seq0 + q0 + r) * QKV_LD + h * HDIM + c * 8);
        *(bf8_t*)&Qs[r * 72 + c * 8] = v;
    }

    f4_t oacc[4] = {};
    float mrow[4], lrow[4];
    #pragma unroll
    for (int r = 0; r < 4; r++) { mrow[r] = -1e30f; lrow[r] = 0.0f; }

    __hip_bfloat16* Pw = Ps + wv * 16 * 136;

    for (int kv0 = 0; kv0 < l; kv0 += 128) {
        __syncthreads();  // protects Qs (1st iter) and Ks/Vs reuse
        // stage K (zero-fill invalid keys)
        #pragma unroll
        for (int i = 0; i < 4; i++) {
            int s = i * 256 + t;
            int key = s >> 3, c = s & 7;
            int tok = kv0 + key;
            bf8_t v = 0;
            if (tok < l)
                v = *(const bf8_t*)(qkv + (long)(seq0 + tok) * QKV_LD + E_DIM + h * HDIM + c * 8);
            *(bf8_t*)&Ks[key * 72 + c * 8] = v;
        }
        // stage V transposed (zero-fill invalid keys: avoids 0 x NaN in PV)
        #pragma unroll
        for (int i = 0; i < 4; i++) {
            int s = i * 256 + t;
            int d = s >> 4, c = s & 15;
            int tb = kv0 + c * 8;
            bf8_t v = 0;
            if (tb + 7 < l) {
                v = *(const bf8_t*)(vt + (long)(h * HDIM + d) * T + seq0 + tb);
            } else if (tb < l) {
                #pragma unroll
                for (int uu = 0; uu < 8; uu++)
                    v[uu] = (tb + uu < l)
                        ? *(const short*)&vt[(long)(h * HDIM + d) * T + seq0 + tb + uu]
                        : (short)0;
            }
            *(bf8_t*)&Vs[d * 136 + c * 8] = v;
        }
        __syncthreads();

        // S = Q K^T  (wave's 16 q-rows x 128 keys)
        bf8_t aq0 = *(const bf8_t*)&Qs[(wv * 16 + m16) * 72 + q4 * 8];
        bf8_t aq1 = *(const bf8_t*)&Qs[(wv * 16 + m16) * 72 + 32 + q4 * 8];
        f4_t S[8];
        #pragma unroll
        for (int nb = 0; nb < 8; nb++) {
            f4_t scc = {};
            scc = mfma16(aq0, *(const bf8_t*)&Ks[(nb * 16 + m16) * 72 + q4 * 8], scc);
            scc = mfma16(aq1, *(const bf8_t*)&Ks[(nb * 16 + m16) * 72 + 32 + q4 * 8], scc);
            S[nb] = scc;
        }

        // mask + row max (C layout: col=lane&15=key, row=q4*4+reg)
        float mx[4];
        #pragma unroll
        for (int r = 0; r < 4; r++) mx[r] = -1e30f;
        #pragma unroll
        for (int nb = 0; nb < 8; nb++) {
            bool valid = (kv0 + nb * 16 + m16) < l;
            #pragma unroll
            for (int r = 0; r < 4; r++) {
                float sv = valid ? S[nb][r] : -1e30f;
                S[nb][r] = sv;
                mx[r] = fmaxf(mx[r], sv);
            }
        }
        #pragma unroll
        for (int r = 0; r < 4; r++) {
            #pragma unroll
            for (int o = 1; o < 16; o <<= 1)
                mx[r] = fmaxf(mx[r], __shfl_xor(mx[r], o));
        }
        float alpha[4];
        #pragma unroll
        for (int r = 0; r < 4; r++) {
            float mn = fmaxf(mrow[r], mx[r]);
            alpha[r] = __expf(mrow[r] - mn);
            mrow[r] = mn;
            lrow[r] *= alpha[r];
        }
        // p = exp(S - m), accumulate lane-partial row sums, write P to per-wave LDS
        #pragma unroll
        for (int nb = 0; nb < 8; nb++) {
            #pragma unroll
            for (int r = 0; r < 4; r++) {
                float p = __expf(S[nb][r] - mrow[r]);
                lrow[r] += p;
                Pw[(q4 * 4 + r) * 136 + nb * 16 + m16] = __float2bfloat16(p);
            }
        }
        #pragma unroll
        for (int nb = 0; nb < 4; nb++)
            #pragma unroll
            for (int r = 0; r < 4; r++)
                oacc[nb][r] *= alpha[r];
        __syncthreads();  // make own P writes LDS-visible before A-frag reads

        // O += P V  (A-layout read of P, B from transposed V tile)
        bf8_t ap[4];
        #pragma unroll
        for (int kc = 0; kc < 4; kc++)
            ap[kc] = *(const bf8_t*)&Pw[m16 * 136 + kc * 32 + q4 * 8];
        #pragma unroll
        for (int nb = 0; nb < 4; nb++) {
            #pragma unroll
            for (int kc = 0; kc < 4; kc++)
                oacc[nb] = mfma16(ap[kc],
                    *(const bf8_t*)&Vs[(nb * 16 + m16) * 136 + kc * 32 + q4 * 8],
                    oacc[nb]);
        }
    }

    // finalize: reduce lane-partial l over the 16 lanes holding each row
    #pragma unroll
    for (int r = 0; r < 4; r++) {
        #pragma unroll
        for (int o = 1; o < 16; o <<= 1)
            lrow[r] += __shfl_xor(lrow[r], o);
    }
    #pragma unroll
    for (int r = 0; r < 4; r++) {
        int qrow = q0 + wv * 16 + q4 * 4 + r;
        if (qrow < l) {
            float inv = 1.0f / lrow[r];
            #pragma unroll
            for (int nb = 0; nb < 4; nb++)
                obuf[(long)(seq0 + qrow) * E_DIM + h * HDIM + nb * 16 + m16] =
                    __float2bfloat16(oacc[nb][r] * inv);
        }
    }
}

// ---------------- launch ----------------
extern "C" void kernel_launch(void* const* d_in, const int* in_sizes, int n_in,
                              void* d_out, int out_size, void* d_ws, size_t ws_size,
                              hipStream_t stream) {
    const int E = E_DIM;
    const int T = in_sizes[0] / E;      // 8192
    const int B = in_sizes[1] - 1;      // 8

    const float* x  = (const float*)d_in[0];
    const int*   cu = (const int*)d_in[1];
    const float* Wq = (const float*)d_in[3];
    const float* bq = (const float*)d_in[4];
    const float* Wk = (const float*)d_in[5];
    const float* bk = (const float*)d_in[6];
    const float* Wv = (const float*)d_in[7];
    const float* bv = (const float*)d_in[8];
    const float* Wo = (const float*)d_in[9];
    const float* bo = (const float*)d_in[10];

    char* ws = (char*)d_ws;
    size_t off = 0;
    auto alloc = [&](size_t bytes) -> void* {
        void* p = ws + off;
        off = (off + bytes + 255) & ~(size_t)255;
        return p;
    };
    __hip_bfloat16* xbf   = (__hip_bfloat16*)alloc((size_t)T * E * 2);
    __hip_bfloat16* wqkv  = (__hip_bfloat16*)alloc((size_t)3 * E * E * 2);
    __hip_bfloat16* wobf  = (__hip_bfloat16*)alloc((size_t)E * E * 2);
    float*          bqkv  = (float*)alloc((size_t)3 * E * 4);
    __hip_bfloat16* qkvb  = (__hip_bfloat16*)alloc((size_t)T * 3 * E * 2);
    __hip_bfloat16* vt    = (__hip_bfloat16*)alloc((size_t)E * T * 2);
    __hip_bfloat16* obuf  = xbf;  // alias: x_bf dead after QKV GEMM, reuse for attention output

    // 1) casts
    long nx8 = (long)T * E / 8;
    long nw8 = (long)E * E / 8;
    long nb8 = (long)3 * E / 8;
    long total = nx8 + 4 * nw8 + nb8;
    int pblocks = (int)((total + 255) / 256);
    prep_kernel<<<pblocks, 256, 0, stream>>>(x, Wq, Wk, Wv, Wo, bq, bk, bv,
                                             xbf, wqkv, wobf, bqkv, nx8, nw8, nb8);

    // 2) fused QKV GEMM (+bias; q already scaled via Wq)
    gemm_nt<true><<<dim3(3 * E / 128, T / 128), 256, 0, stream>>>(
        xbf, wqkv, bqkv, qkvb, T, 3 * E, E, 3 * E);

    // 3) RoPE on q,k
    rope_kernel<<<(int)(((long)T * NHEADS * 32) / 256), 256, 0, stream>>>(qkvb, cu, B, T);

    // 4) V transpose to (h*d, T)
    vtrans_kernel<<<(int)(((long)E * T / 8 + 255) / 256), 256, 0, stream>>>(qkvb, vt, T);

    // 5) flash attention
    int qtiles_ub = T / 64 + B;  // upper bound on sum of per-seq ceil(l/64)
    attn_kernel<<<qtiles_ub * NHEADS, 256, 0, stream>>>(qkvb, vt, cu, obuf, B, T);

    // 6) output projection (fp32 out)
    gemm_nt<false><<<dim3(E / 128, T / 128), 256, 0, stream>>>(
        obuf, wobf, bo, d_out, T, E, E, E);
}